// Round 5
// baseline (338.152 us; speedup 1.0000x reference)
//
#include <hip/hip_runtime.h>
#include <math.h>

#define NTOK  16384   // 4 * 4096 tokens
#define DK    2048    // d_model
#define NEXP  64
#define MTOK  64      // tokens per block
#define NWAVE 8       // waves per block; K split 8-way across waves
#define KSL   (DK / NWAVE)   // 256 k per wave
#define KC    16      // k per staged chunk
#define NCH   (KSL / KC)     // 16 chunks

// Async global->LDS, 16B/lane: HW writes dst + lane*16 (wave-uniform dst base).
__device__ __forceinline__ void gload_lds16(const float* src, float* dst) {
    __builtin_amdgcn_global_load_lds(
        (const __attribute__((address_space(1))) void*)src,
        (__attribute__((address_space(3))) void*)dst, 16, 0, 0);
}

// launch_bounds(512,1): 8-wave block => 2 waves/SIMD co-resident, VGPR cap 256.
// (512,2) in round 4 capped VGPRs at 128 -> 660 MB of scratch spill traffic.
__global__ __launch_bounds__(512, 1) void topk_router_kernel(
    const float* __restrict__ x,     // [NTOK][DK]
    const float* __restrict__ Wg,    // [NEXP][DK]
    float* __restrict__ out)         // [NTOK*2] indices (as float) ++ [NTOK*2] weights
{
    // smem: first 16384 floats = 8 waves x 8KB wave-private x staging
    //       (dbuf x x-tile[64][16]). W is NOT staged (direct global reads).
    // After the epilogue barrier, reused as lg[8][64][68] partial logits.
    __shared__ float smem[34816];    // 139 KiB

    const int tid  = threadIdx.x;
    const int w    = tid >> 6;       // wave 0..7 -> K-slice
    const int lane = tid & 63;
    const int lm   = lane >> 3;      // token-octet: tokens lm*8 .. +7
    const int ln   = lane & 7;       // expert-octet: experts ln*8 .. +7
    const int tok0 = blockIdx.x * MTOK;
    const int k0   = w * KSL;

    float* xpriv = smem + w * 2048;  // this wave's private staging (2 bufs x 4 KB)

    // staging lane decomposition: 64 granules/instr = 16 rows x 4 k-quads
    const int srow = lane >> 2;      // row-within-16
    const int sq4  = (lane & 3) * 4; // k word-quad offset

    float acc[8][8];
    #pragma unroll
    for (int i = 0; i < 8; ++i)
        #pragma unroll
        for (int j = 0; j < 8; ++j) acc[i][j] = 0.f;

    // XOR swizzle on x only: LDS[row][q] holds global k = kc + (q ^ ((row>>3)&3)<<2).
    // Stage applies it on the global SOURCE (dest linear for global_load_lds),
    // read applies it again -> cancels (involution). Read-side rows lm*8+i share
    // sw=(lm&3)<<2; 8 lm-groups map to 4 bank-quads x 2 rows = 2-way = free.
    auto stage = [&](int c, int buf) {
        const int kc = k0 + c * KC;
        float* dstx = xpriv + buf * 1024;
        #pragma unroll
        for (int it = 0; it < 4; ++it) {
            const int row = it * 16 + srow;
            const int wo  = kc + (sq4 ^ (((row >> 3) & 3) << 2));
            gload_lds16(&x[(size_t)(tok0 + row) * DK + wo], dstx + it * 256);
        }
    };

    auto compute = [&](int c, int buf) {
        const float* xb = xpriv + buf * 1024;
        const int swA = (lm & 3) << 2;
        // W rows for this thread's 8 experts, this chunk: exactly one 64B line
        // per row per chunk (KC*4B = 64B) -> L1/L2 friendly, fully reused.
        const float* wbase = Wg + (size_t)(ln * 8) * DK + k0 + c * KC;
        #pragma unroll
        for (int kg = 0; kg < 4; ++kg) {
            float4 a[8], b[8];
            #pragma unroll
            for (int i = 0; i < 8; ++i)
                a[i] = *(const float4*)&xb[(lm * 8 + i) * 16 + ((kg * 4) ^ swA)];
            #pragma unroll
            for (int j = 0; j < 8; ++j)
                b[j] = *(const float4*)(wbase + (size_t)j * DK + kg * 4);
            #pragma unroll
            for (int i = 0; i < 8; ++i)
                #pragma unroll
                for (int j = 0; j < 8; ++j) {
                    acc[i][j] = fmaf(a[i].x, b[j].x, acc[i][j]);
                    acc[i][j] = fmaf(a[i].y, b[j].y, acc[i][j]);
                    acc[i][j] = fmaf(a[i].z, b[j].z, acc[i][j]);
                    acc[i][j] = fmaf(a[i].w, b[j].w, acc[i][j]);
                }
        }
    };

    // ---- prologue: 2 x-chunks in flight (4 global_load_lds each) ----
    stage(0, 0);
    stage(1, 1);

    // ---- main loop: no barriers. vmcnt counting: b-globals are issued AND
    // consumed inside compute (compiler waits them for fmac deps), so at the
    // loop-top wait the only outstanding VMEM are the 2 stages (8 loads);
    // vmcnt(4) retires the older stage. ----
    #pragma unroll 1
    for (int c = 0; c < NCH - 1; ++c) {
        asm volatile("s_waitcnt vmcnt(4)" ::: "memory");  // chunk c landed
        __builtin_amdgcn_sched_barrier(0);
        compute(c, c & 1);
        __builtin_amdgcn_sched_barrier(0);
        if (c + 2 < NCH) stage(c + 2, c & 1);   // refill buffer just freed
    }
    asm volatile("s_waitcnt vmcnt(0)" ::: "memory");
    __builtin_amdgcn_sched_barrier(0);
    compute(NCH - 1, (NCH - 1) & 1);

    // ---- combine 8 K-partials (the only barriers) ----
    __syncthreads();
    {
        float* lg = smem;   // [8][64][68]
        #pragma unroll
        for (int i = 0; i < 8; ++i) {
            float* rowp = lg + ((w * 64) + (lm * 8 + i)) * 68 + ln * 8;
            *(float4*)(rowp)     = make_float4(acc[i][0], acc[i][1], acc[i][2], acc[i][3]);
            *(float4*)(rowp + 4) = make_float4(acc[i][4], acc[i][5], acc[i][6], acc[i][7]);
        }
    }
    __syncthreads();

    // ---- top-2 per token: wave w -> tokens w*8..w*8+7, lane = expert ----
    #pragma unroll 1
    for (int t = 0; t < 8; ++t) {
        const int tok = w * 8 + t;
        float v = 0.f;
        #pragma unroll
        for (int p = 0; p < 8; ++p) v += smem[(p * 64 + tok) * 68 + lane];

        // top-1 (tie -> lower index, matching lax.top_k)
        float m1 = v; int i1 = lane;
        #pragma unroll
        for (int off = 32; off > 0; off >>= 1) {
            float ov = __shfl_xor(m1, off);
            int   oi = __shfl_xor(i1, off);
            if (ov > m1 || (ov == m1 && oi < i1)) { m1 = ov; i1 = oi; }
        }
        // top-2: mask out winner
        float m2 = (lane == i1) ? -INFINITY : v; int i2 = lane;
        #pragma unroll
        for (int off = 32; off > 0; off >>= 1) {
            float ov = __shfl_xor(m2, off);
            int   oi = __shfl_xor(i2, off);
            if (ov > m2 || (ov == m2 && oi < i2)) { m2 = ov; i2 = oi; }
        }

        if (lane == 0) {
            const int gtok = tok0 + tok;
            // softmax denom cancels: w1 = 1/(1+e^{l2-l1}), w2 = 1 - w1
            const float e  = expf(m2 - m1);
            const float w1 = 1.0f / (1.0f + e);
            const float w2 = e / (1.0f + e);
            out[gtok * 2 + 0] = (float)i1;
            out[gtok * 2 + 1] = (float)i2;
            out[NTOK * 2 + gtok * 2 + 0] = w1;
            out[NTOK * 2 + gtok * 2 + 1] = w2;
        }
    }
}

extern "C" void kernel_launch(void* const* d_in, const int* in_sizes, int n_in,
                              void* d_out, int out_size, void* d_ws, size_t ws_size,
                              hipStream_t stream) {
    const float* x  = (const float*)d_in[0];
    const float* Wg = (const float*)d_in[1];
    float* out = (float*)d_out;
    // 256 blocks x 512 threads = 2048 waves (2/SIMD), 1 block/CU, barrier-free K-loop.
    hipLaunchKernelGGL(topk_router_kernel, dim3(NTOK / MTOK), dim3(512), 0, stream,
                       x, Wg, out);
}

// Round 6
// 337.435 us; speedup vs baseline: 1.0021x; 1.0021x over previous
//
#include <hip/hip_runtime.h>
#include <math.h>

#define NTOK  16384   // 4 * 4096 tokens
#define DK    2048    // d_model
#define NEXP  64
#define MTOK  64      // tokens per block
#define KSL   256     // K per wave (8 waves, K split 8-way)
#define KC    16      // k per staged chunk
#define NCH   (KSL / KC)   // 16 chunks

// Async global->LDS, 16B/lane: HW writes dst + lane*16 (wave-uniform dst base).
__device__ __forceinline__ void gload_lds16(const float* src, float* dst) {
    __builtin_amdgcn_global_load_lds(
        (const __attribute__((address_space(1))) void*)src,
        (__attribute__((address_space(3))) void*)dst, 16, 0, 0);
}

// ---- macro-generated, fully scalar hot loop: NO local aggregates that can
// fail SROA. Rounds 4/5 lost 3x to acc[8][8]+a[8]/b[8] landing in scratch
// (WRITE_SIZE 661 MB, VALUBusy 10%). Named float4s are guaranteed mem2reg. ----
#define DOT4(ac, av, bv) \
    ac = fmaf((av).x, (bv).x, ac); ac = fmaf((av).y, (bv).y, ac); \
    ac = fmaf((av).z, (bv).z, ac); ac = fmaf((av).w, (bv).w, ac);

#define ROW8(i) { \
    const float4 av = *(const float4*)&xb[(lm * 8 + (i)) * 16 + kidx]; \
    DOT4(cA##i.x, av, b0) DOT4(cA##i.y, av, b1) \
    DOT4(cA##i.z, av, b2) DOT4(cA##i.w, av, b3) \
    DOT4(cB##i.x, av, b4) DOT4(cB##i.y, av, b5) \
    DOT4(cB##i.z, av, b6) DOT4(cB##i.w, av, b7) }

#define COMPUTE_CHUNK(c, buf) { \
    const float* xb = xpriv + (buf) * 1024; \
    const float* wbase = Wg + (size_t)(ln * 8) * DK + k0 + (c) * KC; \
    _Pragma("unroll") \
    for (int kg = 0; kg < 4; ++kg) { \
        const int kidx = (kg * 4) ^ swA; \
        const float4 b0 = *(const float4*)(wbase + 0 * (size_t)DK + kg * 4); \
        const float4 b1 = *(const float4*)(wbase + 1 * (size_t)DK + kg * 4); \
        const float4 b2 = *(const float4*)(wbase + 2 * (size_t)DK + kg * 4); \
        const float4 b3 = *(const float4*)(wbase + 3 * (size_t)DK + kg * 4); \
        const float4 b4 = *(const float4*)(wbase + 4 * (size_t)DK + kg * 4); \
        const float4 b5 = *(const float4*)(wbase + 5 * (size_t)DK + kg * 4); \
        const float4 b6 = *(const float4*)(wbase + 6 * (size_t)DK + kg * 4); \
        const float4 b7 = *(const float4*)(wbase + 7 * (size_t)DK + kg * 4); \
        ROW8(0) ROW8(1) ROW8(2) ROW8(3) ROW8(4) ROW8(5) ROW8(6) ROW8(7) \
    } }

// Stage one x-chunk [64 tok][16 k] into this wave's private buffer.
// XOR swizzle on the global SOURCE (dest linear for global_load_lds);
// read applies it again -> involution cancels. s(row) = ((row>>3)&3)<<2.
#define STAGE(c, buf) { \
    const int kc = k0 + (c) * KC; \
    float* dstx = xpriv + (buf) * 1024; \
    _Pragma("unroll") \
    for (int it = 0; it < 4; ++it) { \
        const int row = it * 16 + srow; \
        const int wo  = kc + (sq4 ^ (((row >> 3) & 3) << 2)); \
        gload_lds16(&x[(size_t)(tok0 + row) * DK + wo], dstx + it * 256); \
    } }

#define STORE_ROW(i) { \
    float* rp = lg + ((w * 64) + (lm * 8 + (i))) * 68 + ln * 8; \
    *(float4*)rp = cA##i; *(float4*)(rp + 4) = cB##i; }

__global__ __launch_bounds__(512, 1) void topk_router_kernel(
    const float* __restrict__ x,     // [NTOK][DK]
    const float* __restrict__ Wg,    // [NEXP][DK]
    float* __restrict__ out)         // [NTOK*2] indices (as float) ++ [NTOK*2] weights
{
    // smem: first 16384 floats = 8 waves x 8KB wave-private x staging (dbuf).
    // After the epilogue barrier, reused as lg[8][64][68] partial logits.
    __shared__ float smem[34816];    // 139 KiB

    const int tid  = threadIdx.x;
    const int w    = tid >> 6;       // wave 0..7 -> K-slice
    const int lane = tid & 63;
    const int lm   = lane >> 3;      // token-octet: tokens lm*8 .. +7
    const int ln   = lane & 7;       // expert-octet: experts ln*8 .. +7
    const int tok0 = blockIdx.x * MTOK;
    const int k0   = w * KSL;
    const int swA  = (lm & 3) << 2;

    float* xpriv = smem + w * 2048;  // this wave's private staging (2 bufs x 4 KB)

    // staging lane decomposition: 64 granules/instr = 16 rows x 4 k-quads
    const int srow = lane >> 2;      // row-within-16
    const int sq4  = (lane & 3) * 4; // k word-quad offset

    float4 cA0 = {0,0,0,0}, cB0 = {0,0,0,0}, cA1 = {0,0,0,0}, cB1 = {0,0,0,0};
    float4 cA2 = {0,0,0,0}, cB2 = {0,0,0,0}, cA3 = {0,0,0,0}, cB3 = {0,0,0,0};
    float4 cA4 = {0,0,0,0}, cB4 = {0,0,0,0}, cA5 = {0,0,0,0}, cB5 = {0,0,0,0};
    float4 cA6 = {0,0,0,0}, cB6 = {0,0,0,0}, cA7 = {0,0,0,0}, cB7 = {0,0,0,0};

    // ---- prologue: 2 x-chunks in flight (4 global_load_lds each) ----
    STAGE(0, 0);
    STAGE(1, 1);

    // ---- main loop: no barriers. At loop top the only outstanding VMEM are
    // the 2 stages (8 loads); vmcnt(4) retires the older stage. W-loads issue
    // and retire inside COMPUTE via compiler-inserted waits. ----
    #pragma unroll 1
    for (int c = 0; c < NCH - 1; ++c) {
        asm volatile("s_waitcnt vmcnt(4)" ::: "memory");  // chunk c landed
        __builtin_amdgcn_sched_barrier(0);
        COMPUTE_CHUNK(c, c & 1);
        __builtin_amdgcn_sched_barrier(0);
        if (c + 2 < NCH) STAGE(c + 2, c & 1);   // refill buffer just freed
    }
    asm volatile("s_waitcnt vmcnt(0)" ::: "memory");
    __builtin_amdgcn_sched_barrier(0);
    COMPUTE_CHUNK(NCH - 1, (NCH - 1) & 1);

    // ---- combine 8 K-partials (the only barriers) ----
    __syncthreads();
    {
        float* lg = smem;   // [8][64][68]
        STORE_ROW(0) STORE_ROW(1) STORE_ROW(2) STORE_ROW(3)
        STORE_ROW(4) STORE_ROW(5) STORE_ROW(6) STORE_ROW(7)
    }
    __syncthreads();

    // ---- top-2 per token: wave w -> tokens w*8..w*8+7, lane = expert ----
    #pragma unroll 1
    for (int t = 0; t < 8; ++t) {
        const int tok = w * 8 + t;
        float v = 0.f;
        #pragma unroll
        for (int p = 0; p < 8; ++p) v += smem[(p * 64 + tok) * 68 + lane];

        // top-1 (tie -> lower index, matching lax.top_k)
        float m1 = v; int i1 = lane;
        #pragma unroll
        for (int off = 32; off > 0; off >>= 1) {
            float ov = __shfl_xor(m1, off);
            int   oi = __shfl_xor(i1, off);
            if (ov > m1 || (ov == m1 && oi < i1)) { m1 = ov; i1 = oi; }
        }
        // top-2: mask out winner
        float m2 = (lane == i1) ? -INFINITY : v; int i2 = lane;
        #pragma unroll
        for (int off = 32; off > 0; off >>= 1) {
            float ov = __shfl_xor(m2, off);
            int   oi = __shfl_xor(i2, off);
            if (ov > m2 || (ov == m2 && oi < i2)) { m2 = ov; i2 = oi; }
        }

        if (lane == 0) {
            const int gtok = tok0 + tok;
            // softmax denom cancels: w1 = 1/(1+e^{l2-l1}), w2 = 1 - w1
            const float e  = expf(m2 - m1);
            const float w1 = 1.0f / (1.0f + e);
            const float w2 = e / (1.0f + e);
            out[gtok * 2 + 0] = (float)i1;
            out[gtok * 2 + 1] = (float)i2;
            out[NTOK * 2 + gtok * 2 + 0] = w1;
            out[NTOK * 2 + gtok * 2 + 1] = w2;
        }
    }
}

extern "C" void kernel_launch(void* const* d_in, const int* in_sizes, int n_in,
                              void* d_out, int out_size, void* d_ws, size_t ws_size,
                              hipStream_t stream) {
    const float* x  = (const float*)d_in[0];
    const float* Wg = (const float*)d_in[1];
    float* out = (float*)d_out;
    // 256 blocks x 512 threads = 2048 waves (2/SIMD), 1 block/CU, barrier-free K-loop.
    hipLaunchKernelGGL(topk_router_kernel, dim3(NTOK / MTOK), dim3(512), 0, stream,
                       x, Wg, out);
}

// Round 7
// 243.764 us; speedup vs baseline: 1.3872x; 1.3843x over previous
//
#include <hip/hip_runtime.h>
#include <math.h>

#define NTOK  16384   // 4 * 4096 tokens
#define DK    2048    // d_model
#define NEXP  64
#define MTOK  32      // tokens per block
#define KSL   512     // K per wave (4 waves, K split 4-way)
#define KC    16      // k per staged chunk
#define NCH   (KSL / KC)   // 32 chunks

// Async global->LDS, 16B/lane: HW writes dst + lane*16 (wave-uniform dst base).
__device__ __forceinline__ void gload_lds16(const float* src, float* dst) {
    __builtin_amdgcn_global_load_lds(
        (const __attribute__((address_space(1))) void*)src,
        (__attribute__((address_space(3))) void*)dst, 16, 0, 0);
}

// Fully scalar hot loop, named float4 accumulators (4 tok x 8 exp per thread).
// 512-thread blocks were capped at 128 VGPRs by the compiler in rounds 4-6
// (demand ~250 -> 650 MB scratch spill). 256-thread blocks are demand-allocated.
#define DOT4(ac, av, bv) \
    ac = fmaf((av).x, (bv).x, ac); ac = fmaf((av).y, (bv).y, ac); \
    ac = fmaf((av).z, (bv).z, ac); ac = fmaf((av).w, (bv).w, ac);

#define ROW4(i) { \
    const float4 av = *(const float4*)&xb[(lm * 4 + (i)) * 16 + kidx]; \
    DOT4(cA##i.x, av, b0) DOT4(cA##i.y, av, b1) \
    DOT4(cA##i.z, av, b2) DOT4(cA##i.w, av, b3) \
    DOT4(cB##i.x, av, b4) DOT4(cB##i.y, av, b5) \
    DOT4(cB##i.z, av, b6) DOT4(cB##i.w, av, b7) }

#define COMPUTE_CHUNK(c, buf) { \
    const float* xb = xpriv + (buf) * 512; \
    const float* wbase = Wg + (size_t)(ln * 8) * DK + k0 + (c) * KC; \
    _Pragma("unroll") \
    for (int kg = 0; kg < 4; ++kg) { \
        const int kidx = (kg * 4) ^ swA; \
        const float4 b0 = *(const float4*)(wbase + 0 * (size_t)DK + kg * 4); \
        const float4 b1 = *(const float4*)(wbase + 1 * (size_t)DK + kg * 4); \
        const float4 b2 = *(const float4*)(wbase + 2 * (size_t)DK + kg * 4); \
        const float4 b3 = *(const float4*)(wbase + 3 * (size_t)DK + kg * 4); \
        const float4 b4 = *(const float4*)(wbase + 4 * (size_t)DK + kg * 4); \
        const float4 b5 = *(const float4*)(wbase + 5 * (size_t)DK + kg * 4); \
        const float4 b6 = *(const float4*)(wbase + 6 * (size_t)DK + kg * 4); \
        const float4 b7 = *(const float4*)(wbase + 7 * (size_t)DK + kg * 4); \
        ROW4(0) ROW4(1) ROW4(2) ROW4(3) \
    } }

// Stage one x-chunk [32 tok][16 k] into this wave's private buffer (2 instrs).
// XOR swizzle on the global SOURCE (dest linear for global_load_lds); read
// applies it again -> involution cancels. s(row) = ((row>>2)&3)<<2 spreads the
// 8 read-side lm-groups over 4 bank-quads (2-way = free).
#define STAGE(c, buf) { \
    const int kc = k0 + (c) * KC; \
    float* dstx = xpriv + (buf) * 512; \
    _Pragma("unroll") \
    for (int it = 0; it < 2; ++it) { \
        const int row = it * 16 + srow; \
        const int wo  = kc + (sq4 ^ (((row >> 2) & 3) << 2)); \
        gload_lds16(&x[(size_t)(tok0 + row) * DK + wo], dstx + it * 256); \
    } }

#define STORE_ROW(i) { \
    float* rp = lg + ((w * 32) + (lm * 4 + (i))) * 68 + ln * 8; \
    *(float4*)rp = cA##i; *(float4*)(rp + 4) = cB##i; }

__global__ __launch_bounds__(256, 2) void topk_router_kernel(
    const float* __restrict__ x,     // [NTOK][DK]
    const float* __restrict__ Wg,    // [NEXP][DK]
    float* __restrict__ out)         // [NTOK*2] indices (as float) ++ [NTOK*2] weights
{
    // smem overlay: staging = 4 waves x dbuf x [32][16] floats = 16 KB;
    // after the epilogue barrier reused as lg[4][32][68] = 34.8 KB.
    __shared__ float smem[8704];     // 34 KiB -> 2+ blocks/CU by LDS

    const int tid  = threadIdx.x;
    const int w    = tid >> 6;       // wave 0..3 -> K-slice
    const int lane = tid & 63;
    const int lm   = lane >> 3;      // token group: tokens lm*4 .. +3
    const int ln   = lane & 7;       // expert-octet: experts ln*8 .. +7
    const int tok0 = blockIdx.x * MTOK;
    const int k0   = w * KSL;
    const int swA  = (lm & 3) << 2;

    float* xpriv = smem + w * 1024;  // this wave's private staging (2 bufs x 2 KB)

    // staging lane decomposition: 64 granules/instr = 16 rows x 4 k-quads
    const int srow = lane >> 2;      // row-within-16
    const int sq4  = (lane & 3) * 4; // k word-quad offset

    float4 cA0 = {0,0,0,0}, cB0 = {0,0,0,0}, cA1 = {0,0,0,0}, cB1 = {0,0,0,0};
    float4 cA2 = {0,0,0,0}, cB2 = {0,0,0,0}, cA3 = {0,0,0,0}, cB3 = {0,0,0,0};

    // ---- prologue: 2 x-chunks in flight (2 global_load_lds each) ----
    STAGE(0, 0);
    STAGE(1, 1);

    // ---- main loop: no barriers. At loop top the outstanding VMEM are the two
    // stages (4 loads); vmcnt(2) retires the older. W-loads issue and retire
    // inside COMPUTE via compiler-inserted waits (FIFO also retires the
    // just-issued stage before its consumer, keeping the dbuf ordering). ----
    #pragma unroll 1
    for (int c = 0; c < NCH - 1; ++c) {
        asm volatile("s_waitcnt vmcnt(2)" ::: "memory");  // chunk c landed
        __builtin_amdgcn_sched_barrier(0);
        COMPUTE_CHUNK(c, c & 1);
        __builtin_amdgcn_sched_barrier(0);
        if (c + 2 < NCH) STAGE(c + 2, c & 1);   // refill buffer just freed
    }
    asm volatile("s_waitcnt vmcnt(0)" ::: "memory");
    __builtin_amdgcn_sched_barrier(0);
    COMPUTE_CHUNK(NCH - 1, (NCH - 1) & 1);

    // ---- combine 4 K-partials (the only barriers) ----
    __syncthreads();
    {
        float* lg = smem;   // [4][32][68]
        STORE_ROW(0) STORE_ROW(1) STORE_ROW(2) STORE_ROW(3)
    }
    __syncthreads();

    // ---- top-2 per token: wave w -> tokens w*8..w*8+7, lane = expert ----
    #pragma unroll 1
    for (int t = 0; t < 8; ++t) {
        const int tok = w * 8 + t;
        float v = 0.f;
        #pragma unroll
        for (int p = 0; p < 4; ++p) v += smem[(p * 32 + tok) * 68 + lane];

        // top-1 (tie -> lower index, matching lax.top_k)
        float m1 = v; int i1 = lane;
        #pragma unroll
        for (int off = 32; off > 0; off >>= 1) {
            float ov = __shfl_xor(m1, off);
            int   oi = __shfl_xor(i1, off);
            if (ov > m1 || (ov == m1 && oi < i1)) { m1 = ov; i1 = oi; }
        }
        // top-2: mask out winner
        float m2 = (lane == i1) ? -INFINITY : v; int i2 = lane;
        #pragma unroll
        for (int off = 32; off > 0; off >>= 1) {
            float ov = __shfl_xor(m2, off);
            int   oi = __shfl_xor(i2, off);
            if (ov > m2 || (ov == m2 && oi < i2)) { m2 = ov; i2 = oi; }
        }

        if (lane == 0) {
            const int gtok = tok0 + tok;
            // softmax denom cancels: w1 = 1/(1+e^{l2-l1}), w2 = 1 - w1
            const float e  = expf(m2 - m1);
            const float w1 = 1.0f / (1.0f + e);
            const float w2 = e / (1.0f + e);
            out[gtok * 2 + 0] = (float)i1;
            out[gtok * 2 + 1] = (float)i2;
            out[NTOK * 2 + gtok * 2 + 0] = w1;
            out[NTOK * 2 + gtok * 2 + 1] = w2;
        }
    }
}

extern "C" void kernel_launch(void* const* d_in, const int* in_sizes, int n_in,
                              void* d_out, int out_size, void* d_ws, size_t ws_size,
                              hipStream_t stream) {
    const float* x  = (const float*)d_in[0];
    const float* Wg = (const float*)d_in[1];
    float* out = (float*)d_out;
    // 512 blocks x 256 threads = 2048 waves (2/SIMD, 2 blocks/CU), barrier-free K-loop.
    hipLaunchKernelGGL(topk_router_kernel, dim3(NTOK / MTOK), dim3(256), 0, stream,
                       x, Wg, out);
}

// Round 8
// 94.237 us; speedup vs baseline: 3.5883x; 2.5867x over previous
//
#include <hip/hip_runtime.h>
#include <math.h>

#define NTOK  16384   // 4 * 4096 tokens
#define DK    2048    // d_model
#define NEXP  64
#define MTOK  32      // tokens per block
#define KSL   512     // K per wave (4 waves, K split 4-way)
#define KC    16      // k per staged chunk
#define NCH   (KSL / KC)   // 32 chunks

// Async global->LDS, 16B/lane: HW writes dst + lane*16 (wave-uniform dst base).
__device__ __forceinline__ void gload_lds16(const float* src, float* dst) {
    __builtin_amdgcn_global_load_lds(
        (const __attribute__((address_space(1))) void*)src,
        (__attribute__((address_space(3))) void*)dst, 16, 0, 0);
}

// Round-7 lesson: direct global W-gathers (8KB stride = same L1 set) exposed
// ~285 cyc latency PER LOAD serially -> 244us. Fix: W also flows through the
// async global_load_lds pipeline; COMPUTE has zero global loads.
#define DOT4(ac, av, bv) \
    ac = fmaf((av).x, (bv).x, ac); ac = fmaf((av).y, (bv).y, ac); \
    ac = fmaf((av).z, (bv).z, ac); ac = fmaf((av).w, (bv).w, ac);

#define ROW4(i) { \
    const float4 av = *(const float4*)&xb[(lm * 4 + (i)) * 16 + kx]; \
    DOT4(cA##i.x, av, b0) DOT4(cA##i.y, av, b1) \
    DOT4(cA##i.z, av, b2) DOT4(cA##i.w, av, b3) \
    DOT4(cB##i.x, av, b4) DOT4(cB##i.y, av, b5) \
    DOT4(cB##i.z, av, b6) DOT4(cB##i.w, av, b7) }

// All operands from LDS. Read swizzles mirror the stage-side source swizzles
// (involution). a-reads: rows lm*4+i, 2-way max (free). b-reads: rows ln*8+j,
// 8 distinct addrs spread over 4 bank-quads = 2-way (free) + 8-lane broadcast.
#define COMPUTE_CHUNK(buf) { \
    const float* xb  = xpriv + (buf) * 512; \
    const float* wbl = xpriv + 1024 + (buf) * 1024; \
    _Pragma("unroll") \
    for (int kg = 0; kg < 4; ++kg) { \
        const int kx = (kg * 4) ^ swA; \
        const int kw = (kg * 4) ^ swB; \
        const float4 b0 = *(const float4*)&wbl[(ln * 8 + 0) * 16 + kw]; \
        const float4 b1 = *(const float4*)&wbl[(ln * 8 + 1) * 16 + kw]; \
        const float4 b2 = *(const float4*)&wbl[(ln * 8 + 2) * 16 + kw]; \
        const float4 b3 = *(const float4*)&wbl[(ln * 8 + 3) * 16 + kw]; \
        const float4 b4 = *(const float4*)&wbl[(ln * 8 + 4) * 16 + kw]; \
        const float4 b5 = *(const float4*)&wbl[(ln * 8 + 5) * 16 + kw]; \
        const float4 b6 = *(const float4*)&wbl[(ln * 8 + 6) * 16 + kw]; \
        const float4 b7 = *(const float4*)&wbl[(ln * 8 + 7) * 16 + kw]; \
        ROW4(0) ROW4(1) ROW4(2) ROW4(3) \
    } }

// Stage one chunk: x[32 tok][16 k] (2 instrs) + W[64 exp][16 k] (4 instrs).
// XOR swizzle applied to the global SOURCE k-offset (dest linear for
// global_load_lds); the read applies it again -> cancels (involution).
// x: s(row) = ((row>>2)&3)<<2 ; W: s(row) = ((row>>3)&3)<<2.
#define STAGE(c, buf) { \
    const int kc = k0 + (c) * KC; \
    float* dstx = xpriv + (buf) * 512; \
    float* dstw = xpriv + 1024 + (buf) * 1024; \
    _Pragma("unroll") \
    for (int it = 0; it < 2; ++it) { \
        const int row = it * 16 + srow; \
        const int wo  = kc + (sq4 ^ (((row >> 2) & 3) << 2)); \
        gload_lds16(&x[(size_t)(tok0 + row) * DK + wo], dstx + it * 256); \
    } \
    _Pragma("unroll") \
    for (int it = 0; it < 4; ++it) { \
        const int row = it * 16 + srow; \
        const int wo  = kc + (sq4 ^ (((row >> 3) & 3) << 2)); \
        gload_lds16(&Wg[(size_t)row * DK + wo], dstw + it * 256); \
    } }

#define STORE_ROW(i) { \
    float* rp = lg + ((w * 32) + (lm * 4 + (i))) * 68 + ln * 8; \
    *(float4*)rp = cA##i; *(float4*)(rp + 4) = cB##i; }

__global__ __launch_bounds__(256, 2) void topk_router_kernel(
    const float* __restrict__ x,     // [NTOK][DK]
    const float* __restrict__ Wg,    // [NEXP][DK]
    float* __restrict__ out)         // [NTOK*2] indices (as float) ++ [NTOK*2] weights
{
    // Per-wave staging: dbuf x (x[32][16] ++ W[64][16]) = 3072 floats = 12 KB;
    // 4 waves = 48 KB. After the epilogue barrier, overlaid as lg[4][32][68].
    __shared__ float smem[12288];    // 48 KiB -> 2 blocks/CU (grid 512)

    const int tid  = threadIdx.x;
    const int w    = tid >> 6;       // wave 0..3 -> K-slice
    const int lane = tid & 63;
    const int lm   = lane >> 3;      // token group: tokens lm*4 .. +3
    const int ln   = lane & 7;       // expert-octet: experts ln*8 .. +7
    const int tok0 = blockIdx.x * MTOK;
    const int k0   = w * KSL;
    const int swA  = (lm & 3) << 2;
    const int swB  = (ln & 3) << 2;

    float* xpriv = smem + w * 3072;  // this wave's private staging

    // staging lane decomposition: 64 granules/instr = 16 rows x 4 k-quads
    const int srow = lane >> 2;      // row-within-16
    const int sq4  = (lane & 3) * 4; // k word-quad offset

    float4 cA0 = {0,0,0,0}, cB0 = {0,0,0,0}, cA1 = {0,0,0,0}, cB1 = {0,0,0,0};
    float4 cA2 = {0,0,0,0}, cB2 = {0,0,0,0}, cA3 = {0,0,0,0}, cB3 = {0,0,0,0};

    // ---- prologue: 2 chunks in flight (6 global_load_lds each) ----
    STAGE(0, 0);
    STAGE(1, 1);

    // ---- main loop: no barriers, no global loads in COMPUTE. Invariant at
    // loop top: 12 outstanding VMEM = stage(c) 6 + stage(c+1) 6; vmcnt(6)
    // retires stage(c). ----
    #pragma unroll 1
    for (int c = 0; c < NCH - 1; ++c) {
        asm volatile("s_waitcnt vmcnt(6)" ::: "memory");  // chunk c landed
        __builtin_amdgcn_sched_barrier(0);
        COMPUTE_CHUNK(c & 1);
        __builtin_amdgcn_sched_barrier(0);
        if (c + 2 < NCH) STAGE(c + 2, c & 1);   // refill buffer just freed
    }
    asm volatile("s_waitcnt vmcnt(0)" ::: "memory");
    __builtin_amdgcn_sched_barrier(0);
    COMPUTE_CHUNK((NCH - 1) & 1);

    // ---- combine 4 K-partials (the only barriers) ----
    __syncthreads();
    {
        float* lg = smem;   // [4][32][68] overlay
        STORE_ROW(0) STORE_ROW(1) STORE_ROW(2) STORE_ROW(3)
    }
    __syncthreads();

    // ---- top-2 per token: wave w -> tokens w*8..w*8+7, lane = expert ----
    #pragma unroll 1
    for (int t = 0; t < 8; ++t) {
        const int tok = w * 8 + t;
        float v = 0.f;
        #pragma unroll
        for (int p = 0; p < 4; ++p) v += smem[(p * 32 + tok) * 68 + lane];

        // top-1 (tie -> lower index, matching lax.top_k)
        float m1 = v; int i1 = lane;
        #pragma unroll
        for (int off = 32; off > 0; off >>= 1) {
            float ov = __shfl_xor(m1, off);
            int   oi = __shfl_xor(i1, off);
            if (ov > m1 || (ov == m1 && oi < i1)) { m1 = ov; i1 = oi; }
        }
        // top-2: mask out winner
        float m2 = (lane == i1) ? -INFINITY : v; int i2 = lane;
        #pragma unroll
        for (int off = 32; off > 0; off >>= 1) {
            float ov = __shfl_xor(m2, off);
            int   oi = __shfl_xor(i2, off);
            if (ov > m2 || (ov == m2 && oi < i2)) { m2 = ov; i2 = oi; }
        }

        if (lane == 0) {
            const int gtok = tok0 + tok;
            // softmax denom cancels: w1 = 1/(1+e^{l2-l1}), w2 = 1 - w1
            const float e  = expf(m2 - m1);
            const float w1 = 1.0f / (1.0f + e);
            const float w2 = e / (1.0f + e);
            out[gtok * 2 + 0] = (float)i1;
            out[gtok * 2 + 1] = (float)i2;
            out[NTOK * 2 + gtok * 2 + 0] = w1;
            out[NTOK * 2 + gtok * 2 + 1] = w2;
        }
    }
}

extern "C" void kernel_launch(void* const* d_in, const int* in_sizes, int n_in,
                              void* d_out, int out_size, void* d_ws, size_t ws_size,
                              hipStream_t stream) {
    const float* x  = (const float*)d_in[0];
    const float* Wg = (const float*)d_in[1];
    float* out = (float*)d_out;
    // 512 blocks x 256 threads = 2048 waves (2/SIMD, 2 blocks/CU), barrier-free K-loop.
    hipLaunchKernelGGL(topk_router_kernel, dim3(NTOK / MTOK), dim3(256), 0, stream,
                       x, Wg, out);
}

// Round 9
// 87.294 us; speedup vs baseline: 3.8737x; 1.0795x over previous
//
#include <hip/hip_runtime.h>
#include <math.h>

#define NTOK 16384
#define DK   2048
#define NEXP 64

typedef float f32x4 __attribute__((ext_vector_type(4)));
typedef int   i32x4 __attribute__((ext_vector_type(4)));
typedef short s16x8 __attribute__((ext_vector_type(8)));

// ---- scalar RTNE fp32->bf16 (pre-kernel only) ----
__device__ __forceinline__ unsigned short f2bf(float f) {
    union { float f; unsigned u; } v; v.f = f;
    unsigned r = (v.u + 0x7FFFu + ((v.u >> 16) & 1u)) >> 16;
    return (unsigned short)r;
}
__device__ __forceinline__ float bf2f(unsigned short h) {
    union { unsigned u; float f; } v; v.u = ((unsigned)h) << 16;
    return v.f;
}

// Pre-kernel: exact 3-way bf16 split of W into d_ws planes [3][64][2048].
// Residuals are Sterbenz-exact: W = w0+w1+w2 + r, |r| <= 2^-27 |W|.
__global__ __launch_bounds__(256) void wsplit_kernel(const float* __restrict__ Wg,
                                                     unsigned short* __restrict__ ws) {
    const int i = blockIdx.x * 256 + threadIdx.x;    // 131072 elems, grid 512
    const float f = Wg[i];
    const unsigned short h0 = f2bf(f);  const float r1 = f - bf2f(h0);
    const unsigned short h1 = f2bf(r1); const float r2 = r1 - bf2f(h1);
    const unsigned short h2 = f2bf(r2);
    ws[i] = h0; ws[131072 + i] = h1; ws[262144 + i] = h2;
}

// packed fp32->bf16x2 (RTNE), result u32 = [f0 in lo16 | f1 in hi16]
__device__ __forceinline__ unsigned cvtpk(float lo, float hi) {
    unsigned r;
    asm("v_cvt_pk_bf16_f32 %0, %1, %2" : "=v"(r) : "v"(lo), "v"(hi));
    return r;
}

// 3-way split of a float pair straight into the A-fragment u32s (k-even lo16).
#define SPLIT2(F0, F1, O0, O1, O2) { \
    const unsigned q0 = cvtpk((F0), (F1)); \
    const float s0 = (F0) - __builtin_bit_cast(float, q0 << 16); \
    const float s1 = (F1) - __builtin_bit_cast(float, q0 & 0xFFFF0000u); \
    const unsigned q1 = cvtpk(s0, s1); \
    const float t0 = s0 - __builtin_bit_cast(float, q1 << 16); \
    const float t1 = s1 - __builtin_bit_cast(float, q1 & 0xFFFF0000u); \
    O0 = (int)q0; O1 = (int)q1; O2 = (int)cvtpk(t0, t1); }

// Issue round-c loads. Per round: 4 x-float4 + 12 B-i32x4 = 16 VMEM (vmcnt unit).
#define ISSUE_X(XS, c) { \
    _Pragma("unroll") for (int m = 0; m < 2; ++m) \
        _Pragma("unroll") for (int h = 0; h < 2; ++h) \
            XS[m][h] = *(const float4*)(xbase + m * 32768 + h * 4 + (c) * 32); }

#define ISSUE_B(BS, c) { \
    _Pragma("unroll") for (int n = 0; n < 4; ++n) \
        _Pragma("unroll") for (int p = 0; p < 3; ++p) \
            BS[n][p] = *(const i32x4*)(wsbase + (size_t)p * 131072 + n * 32768 + (c) * 32); }

// Convert landed x fp32 (16 elems/lane) into 6 A-frags (2 m x 3 planes).
#define CONV(XS) { \
    _Pragma("unroll") for (int m = 0; m < 2; ++m) { \
        SPLIT2(XS[m][0].x, XS[m][0].y, A[m][0].x, A[m][1].x, A[m][2].x); \
        SPLIT2(XS[m][0].z, XS[m][0].w, A[m][0].y, A[m][1].y, A[m][2].y); \
        SPLIT2(XS[m][1].x, XS[m][1].y, A[m][0].z, A[m][1].z, A[m][2].z); \
        SPLIT2(XS[m][1].z, XS[m][1].w, A[m][0].w, A[m][1].w, A[m][2].w); } }

#define MFMA_TERM(pa, pb, BS) { \
    _Pragma("unroll") for (int m = 0; m < 2; ++m) \
        _Pragma("unroll") for (int n = 0; n < 4; ++n) \
            acc[m][n] = __builtin_amdgcn_mfma_f32_16x16x32_bf16( \
                __builtin_bit_cast(s16x8, A[m][pa]), \
                __builtin_bit_cast(s16x8, BS[n][pb]), acc[m][n], 0, 0, 0); }

// 6 terms cover the product to 2^-27: (0,0),(0,1),(1,0),(1,1),(0,2),(2,0)
#define MFMA_ALL(BS) \
    MFMA_TERM(0, 0, BS) MFMA_TERM(0, 1, BS) MFMA_TERM(1, 0, BS) \
    MFMA_TERM(1, 1, BS) MFMA_TERM(0, 2, BS) MFMA_TERM(2, 0, BS)

// Steady phase: at entry 32 VMEM outstanding (rounds c, c+1); vmcnt(16) lands c.
#define PHASE_MAIN(XS, BS, c) { \
    asm volatile("s_waitcnt vmcnt(16)" ::: "memory"); \
    __builtin_amdgcn_sched_barrier(0); \
    CONV(XS); \
    ISSUE_X(XS, (c) + 2); \
    MFMA_ALL(BS); \
    ISSUE_B(BS, (c) + 2); \
    __builtin_amdgcn_sched_barrier(0); }

__global__ __launch_bounds__(256, 1) void topk_router_kernel(
    const float* __restrict__ x,            // [NTOK][DK] fp32
    const unsigned short* __restrict__ ws,  // [3][64][2048] bf16 W planes
    float* __restrict__ out)                // [NTOK*2] idx (as float) ++ [NTOK*2] w
{
    __shared__ float lg[64][68];            // block logits, +4 pad

    const int tid  = threadIdx.x;
    const int w    = tid >> 6;              // wave 0..3
    const int lane = tid & 63;
    const int tg   = w >> 1;                // token group (32 tokens each)
    const int kh   = w & 1;                 // K-half (1024 each)
    const int rr   = lane & 15;             // frag row/col index
    const int g    = lane >> 4;             // frag k-group (8 k each)
    const int tok0 = blockIdx.x * 64 + tg * 32;

    // A-source: x[tok0+rr + 16m][kh*1024 + 32c + g*8 + 4h]  (frag-layout-direct)
    const float* xbase = x + (size_t)(tok0 + rr) * DK + kh * 1024 + g * 8;
    // B-source: ws plane p, row = 16n+rr (expert), same k slice (L1-resident)
    const unsigned short* wsbase = ws + (size_t)rr * DK + kh * 1024 + g * 8;

    f32x4 acc[2][4];
    #pragma unroll
    for (int m = 0; m < 2; ++m)
        #pragma unroll
        for (int n = 0; n < 4; ++n) acc[m][n] = (f32x4){0.f, 0.f, 0.f, 0.f};

    float4 X0[2][2], X1[2][2];
    i32x4  B0[4][3], B1[4][3];
    i32x4  A[2][3];

    // ---- prologue: rounds 0,1 in flight (16 VMEM each) ----
    ISSUE_X(X0, 0); ISSUE_B(B0, 0);
    ISSUE_X(X1, 1); ISSUE_B(B1, 1);

    // ---- main loop: 32 K32-rounds per wave, no barriers, no LDS ----
    #pragma unroll 1
    for (int c = 0; c < 30; c += 2) {
        PHASE_MAIN(X0, B0, c);
        PHASE_MAIN(X1, B1, c + 1);
    }
    // tail rounds 30, 31
    asm volatile("s_waitcnt vmcnt(16)" ::: "memory");
    __builtin_amdgcn_sched_barrier(0);
    CONV(X0); MFMA_ALL(B0);
    asm volatile("s_waitcnt vmcnt(0)" ::: "memory");
    __builtin_amdgcn_sched_barrier(0);
    CONV(X1); MFMA_ALL(B1);

    // ---- combine K-halves in LDS (D layout: col=lane&15, row=(lane>>4)*4+reg) ----
    if (kh == 0) {
        #pragma unroll
        for (int m = 0; m < 2; ++m)
            #pragma unroll
            for (int n = 0; n < 4; ++n)
                #pragma unroll
                for (int r = 0; r < 4; ++r)
                    lg[tg * 32 + m * 16 + g * 4 + r][n * 16 + rr] = acc[m][n][r];
    }
    __syncthreads();
    if (kh == 1) {
        #pragma unroll
        for (int m = 0; m < 2; ++m)
            #pragma unroll
            for (int n = 0; n < 4; ++n)
                #pragma unroll
                for (int r = 0; r < 4; ++r)
                    lg[tg * 32 + m * 16 + g * 4 + r][n * 16 + rr] += acc[m][n][r];
    }
    __syncthreads();

    // ---- top-2 per token: wave w -> tokens w*16..+15, lane = expert ----
    #pragma unroll 1
    for (int t = 0; t < 16; ++t) {
        const int tok = w * 16 + t;
        const float v = lg[tok][lane];

        // top-1 (tie -> lower index, matching lax.top_k)
        float m1 = v; int i1 = lane;
        #pragma unroll
        for (int off = 32; off > 0; off >>= 1) {
            float ov = __shfl_xor(m1, off);
            int   oi = __shfl_xor(i1, off);
            if (ov > m1 || (ov == m1 && oi < i1)) { m1 = ov; i1 = oi; }
        }
        // top-2: mask out winner
        float m2 = (lane == i1) ? -INFINITY : v; int i2 = lane;
        #pragma unroll
        for (int off = 32; off > 0; off >>= 1) {
            float ov = __shfl_xor(m2, off);
            int   oi = __shfl_xor(i2, off);
            if (ov > m2 || (ov == m2 && oi < i2)) { m2 = ov; i2 = oi; }
        }

        if (lane == 0) {
            const int gtok = blockIdx.x * 64 + tok;
            // softmax denom cancels: w1 = 1/(1+e^{l2-l1}), w2 = 1 - w1
            const float e  = expf(m2 - m1);
            const float w1 = 1.0f / (1.0f + e);
            const float w2 = e / (1.0f + e);
            out[gtok * 2 + 0] = (float)i1;
            out[gtok * 2 + 1] = (float)i2;
            out[NTOK * 2 + gtok * 2 + 0] = w1;
            out[NTOK * 2 + gtok * 2 + 1] = w2;
        }
    }
}

extern "C" void kernel_launch(void* const* d_in, const int* in_sizes, int n_in,
                              void* d_out, int out_size, void* d_ws, size_t ws_size,
                              hipStream_t stream) {
    const float* x  = (const float*)d_in[0];
    const float* Wg = (const float*)d_in[1];
    float* out = (float*)d_out;
    unsigned short* ws = (unsigned short*)d_ws;   // needs 768 KB
    // 1) split W into 3 bf16 planes (exact to 2^-27)
    hipLaunchKernelGGL(wsplit_kernel, dim3(512), dim3(256), 0, stream, Wg, ws);
    // 2) MFMA router: 256 blocks x 256 thr, LDS-free barrier-free main loop
    hipLaunchKernelGGL(topk_router_kernel, dim3(NTOK / 64), dim3(256), 0, stream,
                       x, ws, out);
}